// Round 6
// baseline (211.223 us; speedup 1.0000x reference)
//
#include <hip/hip_runtime.h>
#include <stdint.h>

// ---------------------------------------------------------------------------
// AVFusion round 6: co-resident FF2.
//  Tile 256Mx128N, 8 waves (4Mx2N), BK=32, dbuf LDS 48KB + VGPR<=128
//  (__launch_bounds__(512,4)) -> 2 blocks/CU: one block's store-drain and
//  barrier stalls hide under the other's MFMA. 2-phase prefetch + k-granule
//  XOR swizzle (pre-swizzled global source, rule #21) + setprio.
//  All other kernels unchanged from round 5.
// ---------------------------------------------------------------------------

#define D_MODEL 1024
#define N_HEAD  8
#define DK      128
#define BS      16
#define NSEG    64
#define NSEN    32

typedef __attribute__((ext_vector_type(8))) __bf16 bf16x8;
typedef __attribute__((ext_vector_type(8))) unsigned short u16x8;
typedef __attribute__((ext_vector_type(4))) float f32x4;

__device__ __forceinline__ float bf2f(unsigned short b) {
  union { unsigned int u; float f; } x; x.u = ((unsigned int)b) << 16; return x.f;
}
__device__ __forceinline__ unsigned short f2bf(float f) {
  union { float f; unsigned int u; } x; x.f = f;
  unsigned int u = x.u;
  unsigned int r = (u + 0x7fffu + ((u >> 16) & 1u)) >> 16;  // RNE
  return (unsigned short)r;
}

// async global->LDS, 16B per lane
__device__ __forceinline__ void g2l16(const void* g, void* l) {
  __builtin_amdgcn_global_load_lds(
      (const __attribute__((address_space(1))) void*)g,
      (__attribute__((address_space(3))) void*)l, 16, 0, 0);
}

// ===================== fused fp32->bf16 convert (11 tensors) ===============
struct CvtB { const float* s[11]; unsigned short* d[11]; int n4[11]; };
__global__ __launch_bounds__(256)
void cvtall_kernel(CvtB p) {
  const int z = blockIdx.y;
  const int i = blockIdx.x * 256 + threadIdx.x;
  if (i >= p.n4[z]) return;
  float4 v = reinterpret_cast<const float4*>(p.s[z])[i];
  ushort4 o;
  o.x = f2bf(v.x); o.y = f2bf(v.y); o.z = f2bf(v.z); o.w = f2bf(v.w);
  reinterpret_cast<ushort4*>(p.d[z])[i] = o;
}

// ===================== batched 64x128-tile GEMM (prefetched) ===============
struct GSeg { const unsigned short* A; const unsigned short* B;
              const float* bias; unsigned short* C; };
struct GBatch { GSeg s[3]; int end[3]; };

__global__ __launch_bounds__(256)
void gemm64_bt(GBatch gb) {
  __shared__ __align__(16) unsigned short lA[2][64 * 32];
  __shared__ __align__(16) unsigned short lB[2][128 * 32];

  const int nwg = gridDim.x;                 // multiple of 8
  const int sw = (blockIdx.x & 7) * (nwg >> 3) + (blockIdx.x >> 3);
  int sgi = 0, base = 0;
  if (sw >= gb.end[0]) { sgi = 1; base = gb.end[0]; }
  if (sw >= gb.end[1]) { sgi = 2; base = gb.end[1]; }
  const GSeg sg = gb.s[sgi];
  const int st = sw - base;
  const int m0 = (st >> 3) * 64, n0 = (st & 7) * 128;

  const int t = threadIdx.x;
  const int lane = t & 63, w = t >> 6;
  const int fr = lane & 15, kg = lane >> 4;

  f32x4 acc[2][4] = {};   // [ni][mi], swapped-operand layout

  const int r  = t >> 2;            // 0..63
  const int c8 = (t & 3) * 8;
  const unsigned short* ga  = sg.A + (size_t)(m0 + r) * 1024 + c8;
  const unsigned short* gbp = sg.B + (size_t)(n0 + r) * 1024 + c8;

  auto stage = [&](int buf, int k0) {
    g2l16(ga + k0,              &lA[buf][t * 8]);
    g2l16(gbp + k0,             &lB[buf][t * 8]);
    g2l16(gbp + k0 + 64 * 1024, &lB[buf][2048 + t * 8]);
  };

  stage(0, 0);
  asm volatile("s_waitcnt vmcnt(0)" ::: "memory");
  __syncthreads();

  for (int k0 = 0; k0 < 1024; k0 += 32) {
    const int buf = (k0 >> 5) & 1;
    if (k0 + 32 < 1024) stage(buf ^ 1, k0 + 32);

    u16x8 af[4], bf[2];
#pragma unroll
    for (int mi = 0; mi < 4; ++mi)
      af[mi] = *reinterpret_cast<const u16x8*>(&lA[buf][(mi * 16 + fr) * 32 + kg * 8]);
#pragma unroll
    for (int ni = 0; ni < 2; ++ni)
      bf[ni] = *reinterpret_cast<const u16x8*>(&lB[buf][(w * 32 + ni * 16 + fr) * 32 + kg * 8]);
#pragma unroll
    for (int ni = 0; ni < 2; ++ni)
#pragma unroll
      for (int mi = 0; mi < 4; ++mi)
        acc[ni][mi] = __builtin_amdgcn_mfma_f32_16x16x32_bf16(
            __builtin_bit_cast(bf16x8, bf[ni]), __builtin_bit_cast(bf16x8, af[mi]),
            acc[ni][mi], 0, 0, 0);

    asm volatile("s_waitcnt vmcnt(0)" ::: "memory");
    __syncthreads();
  }

  // swapped D layout: row(N) = kg*4+j, col(M) = fr  -> ushort4 stores
#pragma unroll
  for (int ni = 0; ni < 2; ++ni) {
    const int gn0 = n0 + w * 32 + ni * 16 + kg * 4;
    const float4 bv = *reinterpret_cast<const float4*>(&sg.bias[gn0]);
#pragma unroll
    for (int mi = 0; mi < 4; ++mi) {
      const int gm = m0 + mi * 16 + fr;
      ushort4 o;
      o.x = f2bf(acc[ni][mi][0] + bv.x);
      o.y = f2bf(acc[ni][mi][1] + bv.y);
      o.z = f2bf(acc[ni][mi][2] + bv.z);
      o.w = f2bf(acc[ni][mi][3] + bv.w);
      *reinterpret_cast<ushort4*>(&sg.C[(size_t)gm * 1024 + gn0]) = o;
    }
  }
}

// ========================= FF2: co-resident 256x128 GEMM ===================
// C[M,N] = A[M,K]@B[N,K]^T + bias, fp32 out. M%256==0, N%128==0, K%32==0.
// 8 waves in 4Mx2N grid (per-wave 64x64, acc=64 VGPR). BK=32.
// LDS per buf: A 256x32 @0 (16KB), B 128x32 @16384 (8KB); dbuf -> 48KB.
// 2 blocks/CU co-resident: store-drain of one block hides under the
// other's compute. Slot swizzle: k-granule slot s holds global granule
// s ^ swz(row), swz(row)=(row&3)^((row>>2)&3) -> 2-way bank aliasing (free).
__global__ __launch_bounds__(512, 4)
void ff2_gemm(const unsigned short* __restrict__ A, const unsigned short* __restrict__ B,
              const float* __restrict__ bias, float* __restrict__ C,
              int M, int N, int K) {
  __shared__ __align__(16) unsigned short lds[2 * 12288];   // 48 KB

  const int nwg = gridDim.x;            // %8 == 0
  const int sw = (blockIdx.x & 7) * (nwg >> 3) + (blockIdx.x >> 3);
  const int m0 = (sw >> 3) * 256, n0 = (sw & 7) * 128;

  const int T = threadIdx.x;
  const int lane = T & 63, wave = T >> 6;
  const int wr = wave >> 1, wc = wave & 1;     // 4M x 2N
  const int fr = lane & 15, kg = lane >> 4;
  const int NT = K >> 5;

  char* ldsc = (char*)lds;

  // staging: thread T covers local row (T>>2) within each 128-row call,
  // lds slot (T&3); fetches global k-granule (T&3)^swz(row) (rule #21).
  const int srow = T >> 2;                       // 0..127
  const int gsl = ((T & 3) ^ ((srow & 3) ^ ((srow >> 2) & 3))) * 8;
  const unsigned short* A0 = A + (size_t)(m0 + srow) * K + gsl;
  const unsigned short* A1 = A + (size_t)(m0 + 128 + srow) * K + gsl;
  const unsigned short* B0 = B + (size_t)(n0 + srow) * K + gsl;

  auto stage = [&](int buf, int t) {
    const int kb = t * 32;
    char* dst = ldsc + buf * 24576 + T * 16;
    g2l16(A0 + kb, dst);
    g2l16(A1 + kb, dst + 8192);
    g2l16(B0 + kb, dst + 16384);
  };

  // read addresses (byte offsets within a buffer)
  int raddr[4], baddr[4];
#pragma unroll
  for (int mi = 0; mi < 4; ++mi) {
    int lr = wr * 64 + mi * 16 + fr;
    raddr[mi] = lr * 64 + ((kg ^ ((lr & 3) ^ ((lr >> 2) & 3))) * 16);
  }
#pragma unroll
  for (int ni = 0; ni < 4; ++ni) {
    int lr = wc * 64 + ni * 16 + fr;
    baddr[ni] = 16384 + lr * 64 + ((kg ^ ((lr & 3) ^ ((lr >> 2) & 3))) * 16);
  }

  f32x4 acc[4][4] = {};   // [ni][mi], swapped-operand layout

  stage(0, 0);
  asm volatile("s_waitcnt vmcnt(0)" ::: "memory");
  __builtin_amdgcn_s_barrier();

  for (int t = 0; t < NT; ++t) {
    const int buf = t & 1;
    if (t + 1 < NT) stage(buf ^ 1, t + 1);

    const char* base = ldsc + buf * 24576;
    u16x8 af[4], bf[4];
#pragma unroll
    for (int mi = 0; mi < 4; ++mi)
      af[mi] = *reinterpret_cast<const u16x8*>(base + raddr[mi]);
#pragma unroll
    for (int ni = 0; ni < 4; ++ni)
      bf[ni] = *reinterpret_cast<const u16x8*>(base + baddr[ni]);

    __builtin_amdgcn_s_setprio(1);
#pragma unroll
    for (int ni = 0; ni < 4; ++ni)
#pragma unroll
      for (int mi = 0; mi < 4; ++mi)
        acc[ni][mi] = __builtin_amdgcn_mfma_f32_16x16x32_bf16(
            __builtin_bit_cast(bf16x8, bf[ni]), __builtin_bit_cast(bf16x8, af[mi]),
            acc[ni][mi], 0, 0, 0);
    __builtin_amdgcn_s_setprio(0);

    asm volatile("s_waitcnt vmcnt(0)" ::: "memory");
    __builtin_amdgcn_s_barrier();
  }

  // swapped D layout: row(N) = kg*4+j, col(M) = fr  -> float4 stores
#pragma unroll
  for (int ni = 0; ni < 4; ++ni) {
    const int gn0 = n0 + wc * 64 + ni * 16 + kg * 4;
    const float4 bv = *reinterpret_cast<const float4*>(&bias[gn0]);
#pragma unroll
    for (int mi = 0; mi < 4; ++mi) {
      const int gm = m0 + wr * 64 + mi * 16 + fr;
      float4 o;
      o.x = acc[ni][mi][0] + bv.x;
      o.y = acc[ni][mi][1] + bv.y;
      o.z = acc[ni][mi][2] + bv.z;
      o.w = acc[ni][mi][3] + bv.w;
      *reinterpret_cast<float4*>(&C[(size_t)gm * N + gn0]) = o;
    }
  }
}

// ===================== UA/UV batched small GEMM (prefetched) ===============
__global__ __launch_bounds__(256)
void uav_gemm(const unsigned short* __restrict__ vAV, const unsigned short* __restrict__ w1,
              unsigned short* __restrict__ UAV) {
  __shared__ __align__(16) unsigned short lA[2][128 * 32];
  __shared__ __align__(16) unsigned short lB[2][128 * 32];

  const int zb = blockIdx.z;
  const int tensor = zb >> 3, h = zb & 7;
  const unsigned short* Ab = vAV + (size_t)tensor * (1024 * 1024) + h * 128;
  const unsigned short* Bb = w1 + h * 128;
  unsigned short* Cb = UAV + (size_t)tensor * (1024 * 8192) + h * 1024;

  const int t = threadIdx.x;
  const int m0 = blockIdx.y * 128, n0 = blockIdx.x * 128;
  const int lane = t & 63, wv = t >> 6;
  const int wrow = (wv >> 1) * 64, wcol = (wv & 1) * 64;
  const int fr = lane & 15, kg = lane >> 4;

  f32x4 acc[4][4] = {};   // [ni][mi], swapped-operand layout

  const int r  = t >> 2;
  const int c8 = (t & 3) * 8;
  const unsigned short* ga = Ab + (size_t)(m0 + r) * 1024 + c8;
  const unsigned short* gb = Bb + (size_t)(n0 + r) * 1024 + c8;

  auto stage = [&](int buf, int k0) {
    g2l16(ga + k0,             &lA[buf][t * 8]);
    g2l16(ga + k0 + 64 * 1024, &lA[buf][2048 + t * 8]);
    g2l16(gb + k0,             &lB[buf][t * 8]);
    g2l16(gb + k0 + 64 * 1024, &lB[buf][2048 + t * 8]);
  };

  stage(0, 0);
  asm volatile("s_waitcnt vmcnt(0)" ::: "memory");
  __syncthreads();

  for (int k0 = 0; k0 < 128; k0 += 32) {
    const int buf = (k0 >> 5) & 1;
    if (k0 + 32 < 128) stage(buf ^ 1, k0 + 32);

    u16x8 af[4], bg_[4];
#pragma unroll
    for (int mi = 0; mi < 4; ++mi)
      af[mi] = *reinterpret_cast<const u16x8*>(&lA[buf][(wrow + mi * 16 + fr) * 32 + kg * 8]);
#pragma unroll
    for (int ni = 0; ni < 4; ++ni)
      bg_[ni] = *reinterpret_cast<const u16x8*>(&lB[buf][(wcol + ni * 16 + fr) * 32 + kg * 8]);
#pragma unroll
    for (int ni = 0; ni < 4; ++ni)
#pragma unroll
      for (int mi = 0; mi < 4; ++mi)
        acc[ni][mi] = __builtin_amdgcn_mfma_f32_16x16x32_bf16(
            __builtin_bit_cast(bf16x8, bg_[ni]), __builtin_bit_cast(bf16x8, af[mi]),
            acc[ni][mi], 0, 0, 0);

    asm volatile("s_waitcnt vmcnt(0)" ::: "memory");
    __syncthreads();
  }

#pragma unroll
  for (int ni = 0; ni < 4; ++ni) {
    const int gn0 = n0 + wcol + ni * 16 + kg * 4;
#pragma unroll
    for (int mi = 0; mi < 4; ++mi) {
      const int gm = m0 + wrow + mi * 16 + fr;
      ushort4 o;
      o.x = f2bf(acc[ni][mi][0]);
      o.y = f2bf(acc[ni][mi][1]);
      o.z = f2bf(acc[ni][mi][2]);
      o.w = f2bf(acc[ni][mi][3]);
      *reinterpret_cast<ushort4*>(&Cb[(size_t)gm * 8192 + gn0]) = o;
    }
  }
}

// ============== fused score + hid assembly (one block per (b,g)) ===========
__global__ __launch_bounds__(256)
void score_hid_kernel(const unsigned short* __restrict__ q,
                      const unsigned short* __restrict__ kAV,
                      const unsigned short* __restrict__ UAV,
                      const float* __restrict__ b1,
                      unsigned short* __restrict__ hid) {
  const int bg = blockIdx.x;
  const int b = bg >> 6, g = bg & 63;
  __shared__ float sk[2][D_MODEL];
  __shared__ float pAl[NSEN][N_HEAD];
  const size_t rowA = (size_t)bg * D_MODEL;
  const size_t rowV = rowA + (size_t)BS * NSEG * D_MODEL;
  for (int i = threadIdx.x; i < D_MODEL; i += 256) {
    sk[0][i] = bf2f(kAV[rowA + i]);
    sk[1][i] = bf2f(kAV[rowV + i]);
  }
  __syncthreads();

  const int h = threadIdx.x >> 5;
  const int l = threadIdx.x & 31;
  const float scale = 0.08838834764831845f;  // 1/sqrt(128)

  for (int s = 0; s < NSEN; ++s) {
    const unsigned short* pq = q + ((size_t)(b * NSEN + s)) * D_MODEL + h * DK;
    float la = 0.f, lv = 0.f;
#pragma unroll
    for (int e = 0; e < 4; ++e) {
      int d = l + e * 32;
      float qv = bf2f(pq[d]);
      la += qv * sk[0][h * DK + d];
      lv += qv * sk[1][h * DK + d];
    }
#pragma unroll
    for (int off = 16; off; off >>= 1) {
      la += __shfl_xor(la, off, 32);
      lv += __shfl_xor(lv, off, 32);
    }
    if (l == 0) pAl[s][h] = 1.f / (1.f + __expf((lv - la) * scale));
  }
  __syncthreads();

  const int n0 = threadIdx.x * 4;
  const unsigned short* ua = UAV + (size_t)bg * 8192 + n0;
  const unsigned short* uv = ua + (size_t)1024 * 8192;

  float dU[N_HEAD][4];
  float base[4];
#pragma unroll
  for (int j = 0; j < 4; ++j) base[j] = b1[n0 + j];
#pragma unroll
  for (int hh = 0; hh < N_HEAD; ++hh) {
    ushort4 a4 = *reinterpret_cast<const ushort4*>(ua + hh * 1024);
    ushort4 v4 = *reinterpret_cast<const ushort4*>(uv + hh * 1024);
    float va[4] = {bf2f(a4.x), bf2f(a4.y), bf2f(a4.z), bf2f(a4.w)};
    float vv[4] = {bf2f(v4.x), bf2f(v4.y), bf2f(v4.z), bf2f(v4.w)};
#pragma unroll
    for (int j = 0; j < 4; ++j) { dU[hh][j] = va[j] - vv[j]; base[j] += vv[j]; }
  }

  for (int s = 0; s < NSEN; ++s) {
    float val[4] = {base[0], base[1], base[2], base[3]};
#pragma unroll
    for (int hh = 0; hh < N_HEAD; ++hh) {
      const float p = pAl[s][hh];
#pragma unroll
      for (int j = 0; j < 4; ++j) val[j] = fmaf(p, dU[hh][j], val[j]);
    }
    ushort4 o;
    o.x = f2bf(val[0] > 0.f ? val[0] : 0.f);
    o.y = f2bf(val[1] > 0.f ? val[1] : 0.f);
    o.z = f2bf(val[2] > 0.f ? val[2] : 0.f);
    o.w = f2bf(val[3] > 0.f ? val[3] : 0.f);
    size_t orow = ((size_t)(b * NSEN + s) * NSEG + g) * D_MODEL + n0;
    *reinterpret_cast<ushort4*>(hid + orow) = o;
  }
}

extern "C" void kernel_launch(void* const* d_in, const int* in_sizes, int n_in,
                              void* d_out, int out_size, void* d_ws, size_t ws_size,
                              hipStream_t stream) {
  const float* A  = (const float*)d_in[0];
  const float* V  = (const float*)d_in[1];
  const float* S  = (const float*)d_in[2];
  const float* wA = (const float*)d_in[3];  const float* bA = (const float*)d_in[4];
  const float* wV = (const float*)d_in[5];  const float* bV = (const float*)d_in[6];
  const float* wS = (const float*)d_in[7];  const float* bS = (const float*)d_in[8];
  const float* wq = (const float*)d_in[9];  const float* bq = (const float*)d_in[10];
  const float* wk = (const float*)d_in[11]; const float* bk = (const float*)d_in[12];
  const float* wv = (const float*)d_in[13]; const float* bv = (const float*)d_in[14];
  const float* w1 = (const float*)d_in[15]; const float* b1 = (const float*)d_in[16];
  const float* w2 = (const float*)d_in[17]; const float* b2 = (const float*)d_in[18];

  const int nAV = BS * NSEG * D_MODEL;         // 1,048,576
  const int nS  = BS * NSEN * D_MODEL;         // 524,288
  const int nW  = D_MODEL * D_MODEL;           // 1,048,576
  const int nCT = BS * NSEN * NSEG * D_MODEL;  // 33,554,432
  const int nU  = 2 * 1024 * 8 * 1024;         // 16,777,216

  char* ws = (char*)d_ws;
  size_t off = 0;
  auto carve = [&](size_t elems) {
    unsigned short* p = (unsigned short*)(ws + off);
    off += elems * sizeof(unsigned short);
    return p;
  };
  unsigned short* bwA = carve(nW);
  unsigned short* bwV = carve(nW);
  unsigned short* bwS = carve(nW);
  unsigned short* bwq = carve(nW);
  unsigned short* bwk = carve(nW);
  unsigned short* bwv = carve(nW);
  unsigned short* bw1 = carve(nW);
  unsigned short* bw2 = carve(nW);
  unsigned short* xA  = carve(nAV);
  unsigned short* xV  = carve(nAV);
  unsigned short* xS  = carve(nS);
  unsigned short* A1V1 = carve(2 * nAV);   // A1 rows then V1 rows
  unsigned short* S1  = carve(nS);
  unsigned short* qb  = carve(nS);
  unsigned short* kAV = carve(2 * nAV);    // kA rows then kV rows
  unsigned short* vAV = carve(2 * nAV);    // vA rows then vV rows
  unsigned short* UAV = carve(nU);         // [2][1024][8][1024]
  unsigned short* hid = carve(nCT);        // 64MB
  (void)ws_size; (void)n_in; (void)in_sizes; (void)out_size;

  // 1) all fp32->bf16 converts in one launch
  CvtB cv;
  cv.s[0] = wA; cv.d[0] = bwA; cv.n4[0] = nW / 4;
  cv.s[1] = wV; cv.d[1] = bwV; cv.n4[1] = nW / 4;
  cv.s[2] = wS; cv.d[2] = bwS; cv.n4[2] = nW / 4;
  cv.s[3] = wq; cv.d[3] = bwq; cv.n4[3] = nW / 4;
  cv.s[4] = wk; cv.d[4] = bwk; cv.n4[4] = nW / 4;
  cv.s[5] = wv; cv.d[5] = bwv; cv.n4[5] = nW / 4;
  cv.s[6] = w1; cv.d[6] = bw1; cv.n4[6] = nW / 4;
  cv.s[7] = w2; cv.d[7] = bw2; cv.n4[7] = nW / 4;
  cv.s[8] = A;  cv.d[8] = xA;  cv.n4[8] = nAV / 4;
  cv.s[9] = V;  cv.d[9] = xV;  cv.n4[9] = nAV / 4;
  cv.s[10] = S; cv.d[10] = xS; cv.n4[10] = nS / 4;
  cvtall_kernel<<<dim3(1024, 11), dim3(256), 0, stream>>>(cv);

  // 2) input projections A,V,S in one batched launch
  GBatch pj;
  pj.s[0] = {xA, bwA, bA, A1V1};        pj.end[0] = 128;
  pj.s[1] = {xV, bwV, bV, A1V1 + nAV};  pj.end[1] = 256;
  pj.s[2] = {xS, bwS, bS, S1};          pj.end[2] = 320;
  gemm64_bt<<<dim3(320), 256, 0, stream>>>(pj);

  // 3) q,k,v projections in one batched launch
  GBatch qkv;
  qkv.s[0] = {S1,   bwq, bq, qb};   qkv.end[0] = 64;
  qkv.s[1] = {A1V1, bwk, bk, kAV};  qkv.end[1] = 320;
  qkv.s[2] = {A1V1, bwv, bv, vAV};  qkv.end[2] = 576;
  gemm64_bt<<<dim3(576), 256, 0, stream>>>(qkv);

  // 4) UA/UV batched small GEMMs
  uav_gemm<<<dim3(8, 8, 16), dim3(256), 0, stream>>>(vAV, bw1, UAV);

  // 5) fused scores + hid assembly
  score_hid_kernel<<<dim3(BS * NSEG), dim3(256), 0, stream>>>(qb, kAV, UAV, b1, hid);

  // 6) FF2: co-resident 256x128 schedule, grid = 128 Mtiles * 8 Ntiles = 1024
  ff2_gemm<<<dim3(1024), 512, 0, stream>>>(hid, bw2, b2, (float*)d_out,
                                           32768, 1024, 1024);
}

// Round 7
// 198.921 us; speedup vs baseline: 1.0618x; 1.0618x over previous
//
#include <hip/hip_runtime.h>
#include <stdint.h>

// ---------------------------------------------------------------------------
// AVFusion round 7:
//  - FF2: 256x256 tile, 8 waves (2Mx4N, per-wave 128x64 -> 0.375 LDS-reads
//    per MFMA), BK=32, 3-stage LDS (96KB), counted vmcnt(4), ONE barrier/iter.
//  - gemm64 (pj/qkv): same depth-2 pipeline, 3 bufs (36KB), vmcnt(3).
//  - cvtall / uav / score_hid unchanged from round 6.
// ---------------------------------------------------------------------------

#define D_MODEL 1024
#define N_HEAD  8
#define DK      128
#define BS      16
#define NSEG    64
#define NSEN    32

typedef __attribute__((ext_vector_type(8))) __bf16 bf16x8;
typedef __attribute__((ext_vector_type(8))) unsigned short u16x8;
typedef __attribute__((ext_vector_type(4))) float f32x4;

__device__ __forceinline__ float bf2f(unsigned short b) {
  union { unsigned int u; float f; } x; x.u = ((unsigned int)b) << 16; return x.f;
}
__device__ __forceinline__ unsigned short f2bf(float f) {
  union { float f; unsigned int u; } x; x.f = f;
  unsigned int u = x.u;
  unsigned int r = (u + 0x7fffu + ((u >> 16) & 1u)) >> 16;  // RNE
  return (unsigned short)r;
}

// async global->LDS, 16B per lane
__device__ __forceinline__ void g2l16(const void* g, void* l) {
  __builtin_amdgcn_global_load_lds(
      (const __attribute__((address_space(1))) void*)g,
      (__attribute__((address_space(3))) void*)l, 16, 0, 0);
}

// ===================== fused fp32->bf16 convert (11 tensors) ===============
struct CvtB { const float* s[11]; unsigned short* d[11]; int n4[11]; };
__global__ __launch_bounds__(256)
void cvtall_kernel(CvtB p) {
  const int z = blockIdx.y;
  const int i = blockIdx.x * 256 + threadIdx.x;
  if (i >= p.n4[z]) return;
  float4 v = reinterpret_cast<const float4*>(p.s[z])[i];
  ushort4 o;
  o.x = f2bf(v.x); o.y = f2bf(v.y); o.z = f2bf(v.z); o.w = f2bf(v.w);
  reinterpret_cast<ushort4*>(p.d[z])[i] = o;
}

// ===================== batched 64x128-tile GEMM (depth-2 pipeline) =========
// C[M,1024] = A[M,1024] @ B[1024,1024]^T + bias (bf16 out). Up to 3 segments.
// BM=64, BN=128, BK=32, 4 waves. 3 LDS bufs (12KB each): iter t reads
// buf[t%3] (staged 2 iters ago, landed per counted vmcnt(3)+barrier) and
// stages t+2 into buf[(t+2)%3] (= buffer read at t-1; all waves' reads of it
// retired before this iter's barrier via the auto-lgkmcnt ahead of MFMA).
struct GSeg { const unsigned short* A; const unsigned short* B;
              const float* bias; unsigned short* C; };
struct GBatch { GSeg s[3]; int end[3]; };

__global__ __launch_bounds__(256)
void gemm64_bt(GBatch gb) {
  __shared__ __align__(16) unsigned short lds[3 * 6144];   // 3 x 12KB

  const int nwg = gridDim.x;                 // multiple of 8
  const int sw = (blockIdx.x & 7) * (nwg >> 3) + (blockIdx.x >> 3);
  int sgi = 0, base = 0;
  if (sw >= gb.end[0]) { sgi = 1; base = gb.end[0]; }
  if (sw >= gb.end[1]) { sgi = 2; base = gb.end[1]; }
  const GSeg sg = gb.s[sgi];
  const int st = sw - base;
  const int m0 = (st >> 3) * 64, n0 = (st & 7) * 128;

  const int t = threadIdx.x;
  const int lane = t & 63, w = t >> 6;
  const int fr = lane & 15, kg = lane >> 4;

  f32x4 acc[2][4] = {};   // [ni][mi], swapped-operand layout

  const int r  = t >> 2;            // 0..63
  const int c8 = (t & 3) * 8;
  const unsigned short* ga  = sg.A + (size_t)(m0 + r) * 1024 + c8;
  const unsigned short* gbp = sg.B + (size_t)(n0 + r) * 1024 + c8;
  char* ldsc = (char*)lds;

  auto stage = [&](int buf, int k0) {
    char* d = ldsc + buf * 12288;
    g2l16(ga + k0,              d + t * 16);           // A 4KB
    g2l16(gbp + k0,             d + 4096 + t * 16);    // B rows 0..63
    g2l16(gbp + k0 + 64 * 1024, d + 8192 + t * 16);    // B rows 64..127
  };

  stage(0, 0);
  stage(1, 32);

  const int NT = 32;
  for (int it = 0; it < NT; ++it) {
    if (it < NT - 1) asm volatile("s_waitcnt vmcnt(3)" ::: "memory");
    else             asm volatile("s_waitcnt vmcnt(0)" ::: "memory");
    __builtin_amdgcn_s_barrier();

    const char* bufp = ldsc + (it % 3) * 12288;
    u16x8 af[4], bf[2];
#pragma unroll
    for (int mi = 0; mi < 4; ++mi)
      af[mi] = *reinterpret_cast<const u16x8*>(bufp + (mi * 16 + fr) * 64 + kg * 16);
#pragma unroll
    for (int ni = 0; ni < 2; ++ni)
      bf[ni] = *reinterpret_cast<const u16x8*>(bufp + 4096 + (w * 32 + ni * 16 + fr) * 64 + kg * 16);

    if (it + 2 < NT) stage((it + 2) % 3, (it + 2) * 32);
    __builtin_amdgcn_sched_barrier(0);

    __builtin_amdgcn_s_setprio(1);
#pragma unroll
    for (int ni = 0; ni < 2; ++ni)
#pragma unroll
      for (int mi = 0; mi < 4; ++mi)
        acc[ni][mi] = __builtin_amdgcn_mfma_f32_16x16x32_bf16(
            __builtin_bit_cast(bf16x8, bf[ni]), __builtin_bit_cast(bf16x8, af[mi]),
            acc[ni][mi], 0, 0, 0);
    __builtin_amdgcn_s_setprio(0);
  }

  // swapped D layout: row(N) = kg*4+j, col(M) = fr  -> ushort4 stores
#pragma unroll
  for (int ni = 0; ni < 2; ++ni) {
    const int gn0 = n0 + w * 32 + ni * 16 + kg * 4;
    const float4 bv = *reinterpret_cast<const float4*>(&sg.bias[gn0]);
#pragma unroll
    for (int mi = 0; mi < 4; ++mi) {
      const int gm = m0 + mi * 16 + fr;
      ushort4 o;
      o.x = f2bf(acc[ni][mi][0] + bv.x);
      o.y = f2bf(acc[ni][mi][1] + bv.y);
      o.z = f2bf(acc[ni][mi][2] + bv.z);
      o.w = f2bf(acc[ni][mi][3] + bv.w);
      *reinterpret_cast<ushort4*>(&sg.C[(size_t)gm * 1024 + gn0]) = o;
    }
  }
}

// ========================= FF2: 256x256 deep-pipelined GEMM ================
// C[M,N] = A[M,K]@B[N,K]^T + bias, fp32 out. M%256==0, N%256==0, K%32==0.
// 8 waves 2Mx4N (per-wave 128x64). BK=32. LDS: 3 bufs x (A 16KB + B 16KB).
// Counted vmcnt(4): 2 tiles (4 loads each) in flight; one barrier/iter.
// Granule swizzle: phys k-slot s holds global granule s^swz(row),
// swz(r)=(r&3)^((r>>2)&3); reader uses slot kg^swz(row)  [rule #21].
__global__ __launch_bounds__(512, 2)
void ff2_gemm(const unsigned short* __restrict__ A, const unsigned short* __restrict__ B,
              const float* __restrict__ bias, float* __restrict__ C,
              int M, int N, int K) {
  __shared__ __align__(16) unsigned short lds[3 * 16384];   // 96 KB

  const int nwg = gridDim.x;            // %8 == 0
  const int sw = (blockIdx.x & 7) * (nwg >> 3) + (blockIdx.x >> 3);
  const int m0 = (sw >> 2) * 256, n0 = (sw & 3) * 256;

  const int T = threadIdx.x;
  const int lane = T & 63, wave = T >> 6;
  const int wr = wave >> 2, wc = wave & 3;     // 2M x 4N
  const int fr = lane & 15, kg = lane >> 4;
  const int NT = K >> 5;

  char* ldsc = (char*)lds;

  // staging: thread T covers local row (T>>2) per 128-row call, phys slot T&3;
  // fetches global granule (T&3)^swz(row).
  const int srow = T >> 2;                       // 0..127
  const int gsl = ((T & 3) ^ ((srow & 3) ^ ((srow >> 2) & 3))) * 8;
  const unsigned short* A0 = A + (size_t)(m0 + srow) * K + gsl;
  const unsigned short* A1 = A + (size_t)(m0 + 128 + srow) * K + gsl;
  const unsigned short* B0 = B + (size_t)(n0 + srow) * K + gsl;
  const unsigned short* B1 = B + (size_t)(n0 + 128 + srow) * K + gsl;

  auto stage = [&](int buf, int tt) {
    const int kb = tt * 32;
    char* d = ldsc + buf * 32768 + T * 16;
    g2l16(A0 + kb, d);
    g2l16(A1 + kb, d + 8192);
    g2l16(B0 + kb, d + 16384);
    g2l16(B1 + kb, d + 24576);
  };

  // read byte offsets within a buffer
  int raddr[8], baddr[4];
#pragma unroll
  for (int mi = 0; mi < 8; ++mi) {
    int ra = wr * 128 + mi * 16 + fr;
    raddr[mi] = ra * 64 + ((kg ^ ((ra & 3) ^ ((ra >> 2) & 3))) * 16);
  }
#pragma unroll
  for (int ni = 0; ni < 4; ++ni) {
    int rb = wc * 64 + ni * 16 + fr;
    baddr[ni] = 16384 + rb * 64 + ((kg ^ ((rb & 3) ^ ((rb >> 2) & 3))) * 16);
  }

  f32x4 acc[4][8] = {};   // [ni][mi], swapped-operand layout

  stage(0, 0);
  stage(1, 1);

  for (int t = 0; t < NT; ++t) {
    if (t < NT - 1) asm volatile("s_waitcnt vmcnt(4)" ::: "memory");
    else            asm volatile("s_waitcnt vmcnt(0)" ::: "memory");
    __builtin_amdgcn_s_barrier();

    const char* bufp = ldsc + (t % 3) * 32768;
    u16x8 af[8], bf[4];
#pragma unroll
    for (int mi = 0; mi < 8; ++mi)
      af[mi] = *reinterpret_cast<const u16x8*>(bufp + raddr[mi]);
#pragma unroll
    for (int ni = 0; ni < 4; ++ni)
      bf[ni] = *reinterpret_cast<const u16x8*>(bufp + baddr[ni]);

    if (t + 2 < NT) stage((t + 2) % 3, t + 2);
    __builtin_amdgcn_sched_barrier(0);

    __builtin_amdgcn_s_setprio(1);
#pragma unroll
    for (int ni = 0; ni < 4; ++ni)
#pragma unroll
      for (int mi = 0; mi < 8; ++mi)
        acc[ni][mi] = __builtin_amdgcn_mfma_f32_16x16x32_bf16(
            __builtin_bit_cast(bf16x8, bf[ni]), __builtin_bit_cast(bf16x8, af[mi]),
            acc[ni][mi], 0, 0, 0);
    __builtin_amdgcn_s_setprio(0);
  }

  // swapped D layout: row(N) = kg*4+j, col(M) = fr  -> float4 stores
#pragma unroll
  for (int ni = 0; ni < 4; ++ni) {
    const int gn0 = n0 + wc * 64 + ni * 16 + kg * 4;
    const float4 bv = *reinterpret_cast<const float4*>(&bias[gn0]);
#pragma unroll
    for (int mi = 0; mi < 8; ++mi) {
      const int gm = m0 + wr * 128 + mi * 16 + fr;
      float4 o;
      o.x = acc[ni][mi][0] + bv.x;
      o.y = acc[ni][mi][1] + bv.y;
      o.z = acc[ni][mi][2] + bv.z;
      o.w = acc[ni][mi][3] + bv.w;
      *reinterpret_cast<float4*>(&C[(size_t)gm * N + gn0]) = o;
    }
  }
}

// ===================== UA/UV batched small GEMM (round-6, unchanged) =======
__global__ __launch_bounds__(256)
void uav_gemm(const unsigned short* __restrict__ vAV, const unsigned short* __restrict__ w1,
              unsigned short* __restrict__ UAV) {
  __shared__ __align__(16) unsigned short lA[2][128 * 32];
  __shared__ __align__(16) unsigned short lB[2][128 * 32];

  const int zb = blockIdx.z;
  const int tensor = zb >> 3, h = zb & 7;
  const unsigned short* Ab = vAV + (size_t)tensor * (1024 * 1024) + h * 128;
  const unsigned short* Bb = w1 + h * 128;
  unsigned short* Cb = UAV + (size_t)tensor * (1024 * 8192) + h * 1024;

  const int t = threadIdx.x;
  const int m0 = blockIdx.y * 128, n0 = blockIdx.x * 128;
  const int lane = t & 63, wv = t >> 6;
  const int wrow = (wv >> 1) * 64, wcol = (wv & 1) * 64;
  const int fr = lane & 15, kg = lane >> 4;

  f32x4 acc[4][4] = {};   // [ni][mi], swapped-operand layout

  const int r  = t >> 2;
  const int c8 = (t & 3) * 8;
  const unsigned short* ga = Ab + (size_t)(m0 + r) * 1024 + c8;
  const unsigned short* gb = Bb + (size_t)(n0 + r) * 1024 + c8;

  auto stage = [&](int buf, int k0) {
    g2l16(ga + k0,             &lA[buf][t * 8]);
    g2l16(ga + k0 + 64 * 1024, &lA[buf][2048 + t * 8]);
    g2l16(gb + k0,             &lB[buf][t * 8]);
    g2l16(gb + k0 + 64 * 1024, &lB[buf][2048 + t * 8]);
  };

  stage(0, 0);
  asm volatile("s_waitcnt vmcnt(0)" ::: "memory");
  __syncthreads();

  for (int k0 = 0; k0 < 128; k0 += 32) {
    const int buf = (k0 >> 5) & 1;
    if (k0 + 32 < 128) stage(buf ^ 1, k0 + 32);

    u16x8 af[4], bg_[4];
#pragma unroll
    for (int mi = 0; mi < 4; ++mi)
      af[mi] = *reinterpret_cast<const u16x8*>(&lA[buf][(wrow + mi * 16 + fr) * 32 + kg * 8]);
#pragma unroll
    for (int ni = 0; ni < 4; ++ni)
      bg_[ni] = *reinterpret_cast<const u16x8*>(&lB[buf][(wcol + ni * 16 + fr) * 32 + kg * 8]);
#pragma unroll
    for (int ni = 0; ni < 4; ++ni)
#pragma unroll
      for (int mi = 0; mi < 4; ++mi)
        acc[ni][mi] = __builtin_amdgcn_mfma_f32_16x16x32_bf16(
            __builtin_bit_cast(bf16x8, bg_[ni]), __builtin_bit_cast(bf16x8, af[mi]),
            acc[ni][mi], 0, 0, 0);

    asm volatile("s_waitcnt vmcnt(0)" ::: "memory");
    __syncthreads();
  }

#pragma unroll
  for (int ni = 0; ni < 4; ++ni) {
    const int gn0 = n0 + wcol + ni * 16 + kg * 4;
#pragma unroll
    for (int mi = 0; mi < 4; ++mi) {
      const int gm = m0 + wrow + mi * 16 + fr;
      ushort4 o;
      o.x = f2bf(acc[ni][mi][0]);
      o.y = f2bf(acc[ni][mi][1]);
      o.z = f2bf(acc[ni][mi][2]);
      o.w = f2bf(acc[ni][mi][3]);
      *reinterpret_cast<ushort4*>(&Cb[(size_t)gm * 8192 + gn0]) = o;
    }
  }
}

// ============== fused score + hid assembly (one block per (b,g)) ===========
__global__ __launch_bounds__(256)
void score_hid_kernel(const unsigned short* __restrict__ q,
                      const unsigned short* __restrict__ kAV,
                      const unsigned short* __restrict__ UAV,
                      const float* __restrict__ b1,
                      unsigned short* __restrict__ hid) {
  const int bg = blockIdx.x;
  const int b = bg >> 6, g = bg & 63;
  __shared__ float sk[2][D_MODEL];
  __shared__ float pAl[NSEN][N_HEAD];
  const size_t rowA = (size_t)bg * D_MODEL;
  const size_t rowV = rowA + (size_t)BS * NSEG * D_MODEL;
  for (int i = threadIdx.x; i < D_MODEL; i += 256) {
    sk[0][i] = bf2f(kAV[rowA + i]);
    sk[1][i] = bf2f(kAV[rowV + i]);
  }
  __syncthreads();

  const int h = threadIdx.x >> 5;
  const int l = threadIdx.x & 31;
  const float scale = 0.08838834764831845f;  // 1/sqrt(128)

  for (int s = 0; s < NSEN; ++s) {
    const unsigned short* pq = q + ((size_t)(b * NSEN + s)) * D_MODEL + h * DK;
    float la = 0.f, lv = 0.f;
#pragma unroll
    for (int e = 0; e < 4; ++e) {
      int d = l + e * 32;
      float qv = bf2f(pq[d]);
      la += qv * sk[0][h * DK + d];
      lv += qv * sk[1][h * DK + d];
    }
#pragma unroll
    for (int off = 16; off; off >>= 1) {
      la += __shfl_xor(la, off, 32);
      lv += __shfl_xor(lv, off, 32);
    }
    if (l == 0) pAl[s][h] = 1.f / (1.f + __expf((lv - la) * scale));
  }
  __syncthreads();

  const int n0 = threadIdx.x * 4;
  const unsigned short* ua = UAV + (size_t)bg * 8192 + n0;
  const unsigned short* uv = ua + (size_t)1024 * 8192;

  float dU[N_HEAD][4];
  float base[4];
#pragma unroll
  for (int j = 0; j < 4; ++j) base[j] = b1[n0 + j];
#pragma unroll
  for (int hh = 0; hh < N_HEAD; ++hh) {
    ushort4 a4 = *reinterpret_cast<const ushort4*>(ua + hh * 1024);
    ushort4 v4 = *reinterpret_cast<const ushort4*>(uv + hh * 1024);
    float va[4] = {bf2f(a4.x), bf2f(a4.y), bf2f(a4.z), bf2f(a4.w)};
    float vv[4] = {bf2f(v4.x), bf2f(v4.y), bf2f(v4.z), bf2f(v4.w)};
#pragma unroll
    for (int j = 0; j < 4; ++j) { dU[hh][j] = va[j] - vv[j]; base[j] += vv[j]; }
  }

  for (int s = 0; s < NSEN; ++s) {
    float val[4] = {base[0], base[1], base[2], base[3]};
#pragma unroll
    for (int hh = 0; hh < N_HEAD; ++hh) {
      const float p = pAl[s][hh];
#pragma unroll
      for (int j = 0; j < 4; ++j) val[j] = fmaf(p, dU[hh][j], val[j]);
    }
    ushort4 o;
    o.x = f2bf(val[0] > 0.f ? val[0] : 0.f);
    o.y = f2bf(val[1] > 0.f ? val[1] : 0.f);
    o.z = f2bf(val[2] > 0.f ? val[2] : 0.f);
    o.w = f2bf(val[3] > 0.f ? val[3] : 0.f);
    size_t orow = ((size_t)(b * NSEN + s) * NSEG + g) * D_MODEL + n0;
    *reinterpret_cast<ushort4*>(hid + orow) = o;
  }
}

extern "C" void kernel_launch(void* const* d_in, const int* in_sizes, int n_in,
                              void* d_out, int out_size, void* d_ws, size_t ws_size,
                              hipStream_t stream) {
  const float* A  = (const float*)d_in[0];
  const float* V  = (const float*)d_in[1];
  const float* S  = (const float*)d_in[2];
  const float* wA = (const float*)d_in[3];  const float* bA = (const float*)d_in[4];
  const float* wV = (const float*)d_in[5];  const float* bV = (const float*)d_in[6];
  const float* wS = (const float*)d_in[7];  const float* bS = (const float*)d_in[8];
  const float* wq = (const float*)d_in[9];  const float* bq = (const float*)d_in[10];
  const float* wk = (const float*)d_in[11]; const float* bk = (const float*)d_in[12];
  const float* wv = (const float*)d_in[13]; const float* bv = (const float*)d_in[14];
  const float* w1 = (const float*)d_in[15]; const float* b1 = (const float*)d_in[16];
  const float* w2 = (const float*)d_in[17]; const float* b2 = (const float*)d_in[18];

  const int nAV = BS * NSEG * D_MODEL;         // 1,048,576
  const int nS  = BS * NSEN * D_MODEL;         // 524,288
  const int nW  = D_MODEL * D_MODEL;           // 1,048,576
  const int nCT = BS * NSEN * NSEG * D_MODEL;  // 33,554,432
  const int nU  = 2 * 1024 * 8 * 1024;         // 16,777,216

  char* ws = (char*)d_ws;
  size_t off = 0;
  auto carve = [&](size_t elems) {
    unsigned short* p = (unsigned short*)(ws + off);
    off += elems * sizeof(unsigned short);
    return p;
  };
  unsigned short* bwA = carve(nW);
  unsigned short* bwV = carve(nW);
  unsigned short* bwS = carve(nW);
  unsigned short* bwq = carve(nW);
  unsigned short* bwk = carve(nW);
  unsigned short* bwv = carve(nW);
  unsigned short* bw1 = carve(nW);
  unsigned short* bw2 = carve(nW);
  unsigned short* xA  = carve(nAV);
  unsigned short* xV  = carve(nAV);
  unsigned short* xS  = carve(nS);
  unsigned short* A1V1 = carve(2 * nAV);   // A1 rows then V1 rows
  unsigned short* S1  = carve(nS);
  unsigned short* qb  = carve(nS);
  unsigned short* kAV = carve(2 * nAV);    // kA rows then kV rows
  unsigned short* vAV = carve(2 * nAV);    // vA rows then vV rows
  unsigned short* UAV = carve(nU);         // [2][1024][8][1024]
  unsigned short* hid = carve(nCT);        // 64MB
  (void)ws_size; (void)n_in; (void)in_sizes; (void)out_size;

  // 1) all fp32->bf16 converts in one launch
  CvtB cv;
  cv.s[0] = wA; cv.d[0] = bwA; cv.n4[0] = nW / 4;
  cv.s[1] = wV; cv.d[1] = bwV; cv.n4[1] = nW / 4;
  cv.s[2] = wS; cv.d[2] = bwS; cv.n4[2] = nW / 4;
  cv.s[3] = wq; cv.d[3] = bwq; cv.n4[3] = nW / 4;
  cv.s[4] = wk; cv.d[4] = bwk; cv.n4[4] = nW / 4;
  cv.s[5] = wv; cv.d[5] = bwv; cv.n4[5] = nW / 4;
  cv.s[6] = w1; cv.d[6] = bw1; cv.n4[6] = nW / 4;
  cv.s[7] = w2; cv.d[7] = bw2; cv.n4[7] = nW / 4;
  cv.s[8] = A;  cv.d[8] = xA;  cv.n4[8] = nAV / 4;
  cv.s[9] = V;  cv.d[9] = xV;  cv.n4[9] = nAV / 4;
  cv.s[10] = S; cv.d[10] = xS; cv.n4[10] = nS / 4;
  cvtall_kernel<<<dim3(1024, 11), dim3(256), 0, stream>>>(cv);

  // 2) input projections A,V,S in one batched launch
  GBatch pj;
  pj.s[0] = {xA, bwA, bA, A1V1};        pj.end[0] = 128;
  pj.s[1] = {xV, bwV, bV, A1V1 + nAV};  pj.end[1] = 256;
  pj.s[2] = {xS, bwS, bS, S1};          pj.end[2] = 320;
  gemm64_bt<<<dim3(320), 256, 0, stream>>>(pj);

  // 3) q,k,v projections in one batched launch
  GBatch qkv;
  qkv.s[0] = {S1,   bwq, bq, qb};   qkv.end[0] = 64;
  qkv.s[1] = {A1V1, bwk, bk, kAV};  qkv.end[1] = 320;
  qkv.s[2] = {A1V1, bwv, bv, vAV};  qkv.end[2] = 576;
  gemm64_bt<<<dim3(576), 256, 0, stream>>>(qkv);

  // 4) UA/UV batched small GEMMs
  uav_gemm<<<dim3(8, 8, 16), dim3(256), 0, stream>>>(vAV, bw1, UAV);

  // 5) fused scores + hid assembly
  score_hid_kernel<<<dim3(BS * NSEG), dim3(256), 0, stream>>>(qb, kAV, UAV, b1, hid);

  // 6) FF2: 256x256 deep pipeline, grid = (32768/256)*(1024/256) = 512
  ff2_gemm<<<dim3(512), 512, 0, stream>>>(hid, bw2, b2, (float*)d_out,
                                          32768, 1024, 1024);
}